// Round 8
// baseline (3504.407 us; speedup 1.0000x reference)
//
#include <hip/hip_runtime.h>
#include <hip/hip_fp16.h>
#include <stdint.h>

#define SEQ 512
#define HIDN 512
#define CHAINS 64

typedef _Float16 h2_t __attribute__((ext_vector_type(2)));
typedef _Float16 h8_t __attribute__((ext_vector_type(8)));
typedef float f4_t __attribute__((ext_vector_type(4)));

__device__ __forceinline__ float fdot2f(uint32_t a, uint32_t b, float c) {
#if __has_builtin(__builtin_amdgcn_fdot2)
  return __builtin_amdgcn_fdot2(__builtin_bit_cast(h2_t, a),
                                __builtin_bit_cast(h2_t, b), c, false);
#else
  h2_t ah = __builtin_bit_cast(h2_t, a);
  h2_t bh = __builtin_bit_cast(h2_t, b);
  return c + (float)ah.x * (float)bh.x + (float)ah.y * (float)bh.y;
#endif
}

// ---------------- fp32 -> fp16 convert (contiguous) ----------------
__global__ void k_cvt(const float4* __restrict__ src, __half2* __restrict__ dst, int n4) {
  int i = blockIdx.x * blockDim.x + threadIdx.x;
  if (i < n4) {
    float4 v = src[i];
    dst[2 * i]     = __floats2half2_rn(v.x, v.y);
    dst[2 * i + 1] = __floats2half2_rn(v.z, v.w);
  }
}

// ---------------- transpose + convert: dst[c][r] = (half)src[r][c] ----------------
__global__ void k_transpose_cvt(const float* __restrict__ src, __half* __restrict__ dst,
                                int R, int C) {
  __shared__ float tile[32][33];
  int tx = threadIdx.x, ty = threadIdx.y;
  int c0 = blockIdx.x * 32, r0 = blockIdx.y * 32;
#pragma unroll
  for (int i = 0; i < 4; ++i)
    tile[ty + i * 8][tx] = src[(size_t)(r0 + ty + i * 8) * C + c0 + tx];
  __syncthreads();
#pragma unroll
  for (int i = 0; i < 4; ++i)
    dst[(size_t)(c0 + ty + i * 8) * R + r0 + tx] = __float2half(tile[tx][ty + i * 8]);
}

// ---------------- f16 MFMA GEMM: C(MxN,f32) = A(MxK,f16) * Bt(NxK,f16)^T + bias ----------------
__global__ __launch_bounds__(256, 2) void k_gemm(
    const __half* __restrict__ A, const __half* __restrict__ Bt,
    const float* __restrict__ bias, float* __restrict__ C,
    int M, int N, int K) {
  __shared__ __align__(16) __half As[128 * 32];
  __shared__ __align__(16) __half Bs[128 * 32];
  const int tid = threadIdx.x;
  const int m0 = blockIdx.x * 128;
  const int n0 = blockIdx.y * 128;
  const int w = tid >> 6;
  const int lane = tid & 63;
  const int wm = (w >> 1) * 64;
  const int wn = (w & 1) * 64;
  const int fr = lane & 15;
  const int q = lane >> 4;
  const int lr = tid >> 2;
  const int lc = tid & 3;
  f4_t acc[4][4];
#pragma unroll
  for (int i = 0; i < 4; ++i)
#pragma unroll
    for (int jj = 0; jj < 4; ++jj) acc[i][jj] = (f4_t)(0.f);

  for (int kk = 0; kk < K; kk += 32) {
    *(uint4*)&As[lr * 32 + lc * 8]        = *(const uint4*)&A[(size_t)(m0 + lr) * K + kk + lc * 8];
    *(uint4*)&As[(64 + lr) * 32 + lc * 8] = *(const uint4*)&A[(size_t)(m0 + 64 + lr) * K + kk + lc * 8];
    *(uint4*)&Bs[lr * 32 + lc * 8]        = *(const uint4*)&Bt[(size_t)(n0 + lr) * K + kk + lc * 8];
    *(uint4*)&Bs[(64 + lr) * 32 + lc * 8] = *(const uint4*)&Bt[(size_t)(n0 + 64 + lr) * K + kk + lc * 8];
    __syncthreads();
    h8_t af[4], bf[4];
#pragma unroll
    for (int i = 0; i < 4; ++i) {
      af[i] = *(const h8_t*)&As[(wm + i * 16 + fr) * 32 + q * 8];
      bf[i] = *(const h8_t*)&Bs[(wn + i * 16 + fr) * 32 + q * 8];
    }
#pragma unroll
    for (int i = 0; i < 4; ++i)
#pragma unroll
      for (int jj = 0; jj < 4; ++jj)
        acc[i][jj] = __builtin_amdgcn_mfma_f32_16x16x32_f16(af[i], bf[jj], acc[i][jj], 0, 0, 0);
    __syncthreads();
  }
#pragma unroll
  for (int i = 0; i < 4; ++i) {
    const int row0 = m0 + wm + i * 16 + q * 4;
#pragma unroll
    for (int jj = 0; jj < 4; ++jj) {
      const int col = n0 + wn + jj * 16 + fr;
      const float bv = bias[col];
#pragma unroll
      for (int r = 0; r < 4; ++r)
        C[(size_t)(row0 + r) * N + col] = acc[i][jj][r] + bv;
    }
  }
}

// ---------------- serial recurrence: 4 CUs per chain, 256 blocks ----------------
// Law from R2-R7: per-CU weight delivery caps at ~85-100 B/cyc on EVERY path,
// so a single-CU chain (512 KB/step) floors at ~4000 cyc/step (R6=862us).
// Fix: split each (batch,dir) chain over 4 CUs. Block owns 128 cols x 512 K
// = 128 KB weights, ALL LDS-resident -> 1536 cyc/step weight reads.
// h-slices exchanged via L2 (double-buffered Hx) with device-scope
// release/acquire flags. blockIdx%8 = XCD heuristic keeps a chain's 4 blocks
// on one XCD. Grid=256=#CUs, 1 block/CU (133KB LDS) => co-resident.
__global__ __launch_bounds__(1024) void k_rnn(
    const __half* __restrict__ WhT_f, const __half* __restrict__ WhT_b,
    const float* __restrict__ A_f, const float* __restrict__ A_b,
    __half* __restrict__ bi, __half* __restrict__ Hx,
    unsigned int* __restrict__ flags) {
  __shared__ __align__(16) uint4 w4[8192];       // 128 KB: [(ks*8+u)*128 + col]
  __shared__ __align__(16) __half hbuf[HIDN];    // 1 KB
  __shared__ float psum[1024];                   // 4 KB: [ks*128 + col]
  const int t = threadIdx.x;
  const int B = blockIdx.x;
  const int xcd = B & 7, q = B >> 3;
  const int part = q & 3, slot = q >> 2;
  const int c = slot * 8 + xcd;                  // chain 0..63 (4 blocks share c)
  const int d = c & 1, b = c >> 1;
  const int c0 = part * 128;                     // this block's column base
  const __half* WhT = d ? WhT_b : WhT_f;         // WhT[j][k] = Wh[k][j]
  const float* A = (d ? A_b : A_f) + (size_t)b * SEQ * HIDN;
  const int col = t & 127, ks = t >> 7;          // ks wave-uniform (t>>7)

  // stage this block's weight slice: cols c0..c0+127, all K (one-time, L2-hot)
  {
    const uint4* wr = (const uint4*)(WhT + (size_t)(c0 + col) * HIDN);
#pragma unroll
    for (int u = 0; u < 8; ++u) w4[(ks * 8 + u) * 128 + col] = wr[ks * 8 + u];
  }
  if (t < HIDN) hbuf[t] = __float2half(0.f);
  __syncthreads();

  unsigned int* myflags = flags + c * 4;
  const int tstep = d ? -1 : 1;
  int tt = d ? (SEQ - 1) : 0;
  float a_next = (t < 128) ? A[(size_t)tt * HIDN + c0 + t] : 0.f;

  for (int s = 0; s < SEQ; ++s) {
    // ---- phase A: partial dot over this thread's (col, 64-elem K-slice) ----
    const uint4* hp = (const uint4*)hbuf + ks * 8;   // wave-uniform broadcast
    float ac0 = 0.f, ac1 = 0.f, ac2 = 0.f, ac3 = 0.f;
#pragma unroll
    for (int u = 0; u < 8; ++u) {
      uint4 hv = hp[u];
      uint4 w = w4[(ks * 8 + u) * 128 + col];
      ac0 = fdot2f(hv.x, w.x, ac0);
      ac1 = fdot2f(hv.y, w.y, ac1);
      ac2 = fdot2f(hv.z, w.z, ac2);
      ac3 = fdot2f(hv.w, w.w, ac3);
    }
    psum[ks * 128 + col] = (ac0 + ac1) + (ac2 + ac3);
    __syncthreads();
    // ---- phase B: combine + tanh + publish slice to L2 ----
    __half* HxS = Hx + ((size_t)(s & 1) * CHAINS + c) * HIDN;
    if (t < 128) {
      float p = a_next;
#pragma unroll
      for (int u = 0; u < 8; ++u) p += psum[u * 128 + t];
      float ap = fabsf(p);
      float e = __expf(2.f * ap);
      float th = 1.f - 2.f * __builtin_amdgcn_rcpf(e + 1.f);  // tanh(|p|)
      float h = copysignf(th, p);
      __half hh = __float2half(h);
      HxS[c0 + t] = hh;
      bi[(size_t)b * SEQ * 1024 + (size_t)tt * 1024 + d * HIDN + c0 + t] = hh;
      int tn = tt + tstep;
      tn = tn < 0 ? 0 : (tn > SEQ - 1 ? SEQ - 1 : tn);
      a_next = A[(size_t)tn * HIDN + c0 + t];    // prefetch next step
    }
    __syncthreads();   // drains vmcnt -> all Hx stores L2-visible
    if (t == 0)
      __hip_atomic_store(&myflags[part], (unsigned int)(s + 1),
                         __ATOMIC_RELEASE, __HIP_MEMORY_SCOPE_AGENT);
    if (t < 4) {
      while (__hip_atomic_load(&myflags[t], __ATOMIC_ACQUIRE,
                               __HIP_MEMORY_SCOPE_AGENT) <= (unsigned int)s) {}
    }
    __syncthreads();
    // ---- refill full h from Hx (own + 3 partners) ----
    if (t < 256) ((unsigned int*)hbuf)[t] = ((const unsigned int*)HxS)[t];
    tt += tstep;
    __syncthreads();
  }
}

extern "C" void kernel_launch(void* const* d_in, const int* in_sizes, int n_in,
                              void* d_out, int out_size, void* d_ws, size_t ws_size,
                              hipStream_t stream) {
  const float* input_seq = (const float*)d_in[0];  // (32,512,512)
  const float* W_f = (const float*)d_in[1];        // (1024,512)
  const float* b_f = (const float*)d_in[2];
  const float* W_b = (const float*)d_in[3];
  const float* b_b = (const float*)d_in[4];
  const float* W_o = (const float*)d_in[5];        // (1024,512)
  const float* b_o = (const float*)d_in[6];
  float* out = (float*)d_out;

  char* ws = (char*)d_ws;
  __half* Xh    = (__half*)(ws);                    // 16 MB  (16384x512 f16)
  float*  A_f   = (float*)(ws + 16777216);          // 32 MB
  float*  A_b   = (float*)(ws + 50331648);          // 32 MB
  __half* bi    = (__half*)(ws + 83886080);         // 32 MB  (16384x1024 f16)
  __half* WxT_f = (__half*)(ws + 117440512);        // 512 KB
  __half* WxT_b = (__half*)(ws + 117964800);
  __half* WhT_f = (__half*)(ws + 118489088);        // 512 KB
  __half* WhT_b = (__half*)(ws + 119013376);
  __half* WoT   = (__half*)(ws + 119537664);        // 1 MB   (512x1024, [o][c])
  __half* Hx    = (__half*)(ws + 120586240);        // 128 KB (2x64x512 f16 dbuf)
  unsigned int* flags = (unsigned int*)(ws + 120717312);  // 1 KB (64x4 u32)

  hipMemsetAsync(flags, 0, CHAINS * 4 * sizeof(unsigned int), stream);

  k_cvt<<<8192, 256, 0, stream>>>((const float4*)input_seq, (__half2*)Xh, 2097152);
  dim3 tb(32, 8);
  k_transpose_cvt<<<dim3(16, 16), tb, 0, stream>>>(W_f,          WxT_f, 512, 512);
  k_transpose_cvt<<<dim3(16, 16), tb, 0, stream>>>(W_f + 262144, WhT_f, 512, 512);
  k_transpose_cvt<<<dim3(16, 16), tb, 0, stream>>>(W_b,          WxT_b, 512, 512);
  k_transpose_cvt<<<dim3(16, 16), tb, 0, stream>>>(W_b + 262144, WhT_b, 512, 512);
  k_transpose_cvt<<<dim3(16, 32), tb, 0, stream>>>(W_o,          WoT, 1024, 512);

  k_gemm<<<dim3(128, 4), 256, 0, stream>>>(Xh, WxT_f, b_f, A_f, 16384, 512, 512);
  k_gemm<<<dim3(128, 4), 256, 0, stream>>>(Xh, WxT_b, b_b, A_b, 16384, 512, 512);

  k_rnn<<<256, 1024, 0, stream>>>(WhT_f, WhT_b, A_f, A_b, bi, Hx, flags);

  k_gemm<<<dim3(128, 4), 256, 0, stream>>>(bi, WoT, b_o, out, 16384, 512, 1024);
}